// Round 1
// baseline (883.712 us; speedup 1.0000x reference)
//
#include <hip/hip_runtime.h>
#include <stdint.h>

#define N_NODES 20000
#define K_COL 16
#define C_IN 256
#define NODES_PER_BLOCK 4
#define ROWS 64              /* NODES_PER_BLOCK * K_COL */
#define APITCH 264           /* 256 + 8 bf16 pad -> conflict-free ds_read_b128 */
#define ZPITCH 260           /* +4 float pad -> quads hit distinct banks */

typedef __attribute__((ext_vector_type(8))) short bf16x8;
typedef __attribute__((ext_vector_type(4))) float f32x4;

static __device__ __forceinline__ unsigned short f2b(float x) {
    union { float f; uint32_t u; } c; c.f = x;
    uint32_t r = c.u + 0x7fffu + ((c.u >> 16) & 1u);   // RNE bf16
    return (unsigned short)(r >> 16);
}
static __device__ __forceinline__ float b2f(unsigned short h) {
    union { uint32_t u; float f; } c; c.u = ((uint32_t)h) << 16;
    return c.f;
}
static __device__ __forceinline__ bf16x8 cvt8(const float* __restrict__ p) {
    const float4 a = *(const float4*)(p);
    const float4 b = *(const float4*)(p + 4);
    bf16x8 v;
    v[0] = (short)f2b(a.x); v[1] = (short)f2b(a.y);
    v[2] = (short)f2b(a.z); v[3] = (short)f2b(a.w);
    v[4] = (short)f2b(b.x); v[5] = (short)f2b(b.y);
    v[6] = (short)f2b(b.z); v[7] = (short)f2b(b.w);
    return v;
}
static __device__ __forceinline__ f32x4 zero4() {
    f32x4 z; z[0] = 0.f; z[1] = 0.f; z[2] = 0.f; z[3] = 0.f; return z;
}

// mask dtype probe: reference dtype is bool; harness may ship 1-byte bool or
// int32 (0/1). If int32, bytes at non-word-aligned offsets are all zero.
__global__ void detect_mask_kernel(const unsigned char* __restrict__ m, int* flag) {
    const int t = threadIdx.x;   // 64 threads, inspect first 1024 bytes
    int nz = 0;
#pragma unroll
    for (int i = 0; i < 16; ++i) {
        const int idx = t * 16 + i;
        if (idx & 3) nz |= m[idx];
    }
    const unsigned long long b = __ballot(nz != 0);
    if (t == 0) *flag = (b == 0ULL) ? 1 : 0;   // 1 => int32-encoded mask
}

__global__ __launch_bounds__(256, 2)
void fused_utou_kernel(const float* __restrict__ u,
                       const float* __restrict__ n_batch,
                       const float* __restrict__ W1,
                       const float* __restrict__ b1,
                       const float* __restrict__ W2,
                       const float* __restrict__ W3,
                       const void* __restrict__ maskp,
                       const int* __restrict__ coloring,
                       const int* __restrict__ mask_flag,
                       float* __restrict__ out)
{
    __shared__ unsigned short Abuf[ROWS][APITCH];   // u tile, bf16
    __shared__ unsigned short A2buf[16][APITCH];    // mean2 rows 0..3 (+unused pad rows)
    __shared__ float zbuf2[NODES_PER_BLOCK][ZPITCH];
    __shared__ float zbuf3[NODES_PER_BLOCK][ZPITCH];

    const int t = threadIdx.x;
    const int nb = blockIdx.x * NODES_PER_BLOCK;
    const long long row0 = (long long)nb * K_COL;

    // ---- Phase 1: stage u tile fp32->bf16; fp32 mean2 computed in-flight ----
    {
        const int nd = t >> 6;          // node in block == wave id
        const int co = t & 63;          // column quad (4 floats)
        const float inv_nb = 1.0f / n_batch[nb + nd];
        const float* up = u + (row0 + (long long)nd * K_COL) * C_IN + co * 4;
        float s0 = 0.f, s1 = 0.f, s2 = 0.f, s3 = 0.f;
#pragma unroll
        for (int r = 0; r < K_COL; ++r) {
            const float4 v = *(const float4*)(up + r * C_IN);  // coalesced: wave reads full 1KB row
            s0 += v.x; s1 += v.y; s2 += v.z; s3 += v.w;
            ushort4 h;
            h.x = f2b(v.x); h.y = f2b(v.y); h.z = f2b(v.z); h.w = f2b(v.w);
            *(ushort4*)&Abuf[nd * K_COL + r][co * 4] = h;
        }
        ushort4 m;
        m.x = f2b(s0 * inv_nb); m.y = f2b(s1 * inv_nb);
        m.z = f2b(s2 * inv_nb); m.w = f2b(s3 * inv_nb);
        *(ushort4*)&A2buf[nd][co * 4] = m;
        // A2buf rows 4..15 stay uninitialized: garbage A rows only affect
        // C rows 4..15, which are never read.
    }
    __syncthreads();

    const int l = t & 63;
    const int lm = l & 15;
    const int quad = l >> 4;
    const int obase = (t >> 6) * 64;   // each wave owns 64 output columns

    // ---- Phase 2: z2 = 0.1*mean2@W2^T, z3 = 0.1*mean2@W3^T (one 16-row MFMA tile) ----
    {
        f32x4 acc2[4] = {zero4(), zero4(), zero4(), zero4()};
        f32x4 acc3[4] = {zero4(), zero4(), zero4(), zero4()};
#pragma unroll
        for (int kt = 0; kt < 8; ++kt) {
            const int kof = kt * 32 + quad * 8;
            const bf16x8 a2 = *(const bf16x8*)&A2buf[lm][kof];
#pragma unroll
            for (int nt = 0; nt < 4; ++nt) {
                const int o = obase + nt * 16 + lm;
                const bf16x8 b2 = cvt8(W2 + o * C_IN + kof);
                acc2[nt] = __builtin_amdgcn_mfma_f32_16x16x32_bf16(a2, b2, acc2[nt], 0, 0, 0);
                const bf16x8 b3 = cvt8(W3 + o * C_IN + kof);
                acc3[nt] = __builtin_amdgcn_mfma_f32_16x16x32_bf16(a2, b3, acc3[nt], 0, 0, 0);
            }
        }
        // C/D: col = lane&15, row = quad*4 + reg. Mean rows 0..3 live in quad 0.
        if (quad == 0) {
#pragma unroll
            for (int nt = 0; nt < 4; ++nt) {
#pragma unroll
                for (int r = 0; r < 4; ++r) {
                    const int col = obase + nt * 16 + lm;
                    zbuf2[r][col] = 0.1f * acc2[nt][r];
                    zbuf3[r][col] = 0.1f * acc3[nt][r];
                }
            }
        }
    }
    __syncthreads();

    // ---- Phase 3: main GEMM  [64 x 256] @ W1^T, W1 frags streamed from L2 ----
    f32x4 acc[4][4];
#pragma unroll
    for (int mt = 0; mt < 4; ++mt)
#pragma unroll
        for (int nt = 0; nt < 4; ++nt) acc[mt][nt] = zero4();

#pragma unroll
    for (int kt = 0; kt < 8; ++kt) {
        const int kof = kt * 32 + quad * 8;
        bf16x8 bfr[4];
#pragma unroll
        for (int nt = 0; nt < 4; ++nt)
            bfr[nt] = cvt8(W1 + (obase + nt * 16 + lm) * C_IN + kof);
#pragma unroll
        for (int mt = 0; mt < 4; ++mt) {
            const bf16x8 af = *(const bf16x8*)&Abuf[mt * 16 + lm][kof];
#pragma unroll
            for (int nt = 0; nt < 4; ++nt)
                acc[mt][nt] = __builtin_amdgcn_mfma_f32_16x16x32_bf16(af, bfr[nt], acc[mt][nt], 0, 0, 0);
        }
    }

    // ---- Phase 4: epilogue  u + out + b1 + scatter(z2) + mask*z3 ----
    const bool mask_is_i32 = (*mask_flag != 0);
    const int* mi = (const int*)maskp;
    const unsigned char* mb = (const unsigned char*)maskp;
    float b1v[4];
#pragma unroll
    for (int nt = 0; nt < 4; ++nt) b1v[nt] = b1[obase + nt * 16 + lm];

#pragma unroll
    for (int mt = 0; mt < 4; ++mt) {
#pragma unroll
        for (int r = 0; r < 4; ++r) {
            const int row = mt * 16 + quad * 4 + r;   // tile row = M index
            const int node = row >> 4;
            const int kc = row & 15;
            const long long rg = row0 + row;          // == flat (n,k) == mask index
            const bool sel = (coloring[nb + node] == kc);
            const bool mk = mask_is_i32 ? (mi[rg] != 0) : (mb[rg] != 0);
            float* orow = out + rg * C_IN;
#pragma unroll
            for (int nt = 0; nt < 4; ++nt) {
                const int col = obase + nt * 16 + lm;
                float v = acc[mt][nt][r] + b1v[nt] + b2f(Abuf[row][col]);
                v += sel ? zbuf2[node][col] : 0.0f;
                v += mk ? zbuf3[node][col] : 0.0f;
                orow[col] = v;   // 16 lanes -> 64B contiguous per row-quad
            }
        }
    }
}

extern "C" void kernel_launch(void* const* d_in, const int* in_sizes, int n_in,
                              void* d_out, int out_size, void* d_ws, size_t ws_size,
                              hipStream_t stream) {
    const float* u        = (const float*)d_in[0];
    const float* nbt      = (const float*)d_in[1];
    const float* W1       = (const float*)d_in[2];
    const float* b1       = (const float*)d_in[3];
    const float* W2       = (const float*)d_in[4];
    const float* W3       = (const float*)d_in[5];
    const void*  mask     = d_in[6];
    const int*   coloring = (const int*)d_in[7];
    float* out = (float*)d_out;
    int* flag = (int*)d_ws;

    detect_mask_kernel<<<1, 64, 0, stream>>>((const unsigned char*)mask, flag);
    fused_utou_kernel<<<N_NODES / NODES_PER_BLOCK, 256, 0, stream>>>(
        u, nbt, W1, b1, W2, W3, mask, coloring, flag, out);
}

// Round 2
// 600.643 us; speedup vs baseline: 1.4713x; 1.4713x over previous
//
#include <hip/hip_runtime.h>
#include <stdint.h>

#define N_NODES 20000
#define K_COL 16
#define C_IN 256
#define NODES_PER_BLOCK 4
#define ROWS 64              /* NODES_PER_BLOCK * K_COL */
#define APITCH 264           /* 256 + 8 bf16 pad -> conflict-free ds_read_b128 */
#define ZPITCH 260

#define WS_FLAG_OFF 0
#define WS_WB_OFF   256
#define WB_MAT_ELEMS (256 * 256)                 /* bf16 elements per matrix */
#define WS_NEEDED   (WS_WB_OFF + 3 * WB_MAT_ELEMS * 2)

typedef __attribute__((ext_vector_type(8))) short bf16x8;
typedef __attribute__((ext_vector_type(4))) float f32x4;

static __device__ __forceinline__ unsigned short f2b(float x) {
    union { float f; uint32_t u; } c; c.f = x;
    uint32_t r = c.u + 0x7fffu + ((c.u >> 16) & 1u);   // RNE bf16
    return (unsigned short)(r >> 16);
}
static __device__ __forceinline__ float b2f(unsigned short h) {
    union { uint32_t u; float f; } c; c.u = ((uint32_t)h) << 16;
    return c.f;
}
static __device__ __forceinline__ bf16x8 cvt8(const float* __restrict__ p) {
    const float4 a = *(const float4*)(p);
    const float4 b = *(const float4*)(p + 4);
    bf16x8 v;
    v[0] = (short)f2b(a.x); v[1] = (short)f2b(a.y);
    v[2] = (short)f2b(a.z); v[3] = (short)f2b(a.w);
    v[4] = (short)f2b(b.x); v[5] = (short)f2b(b.y);
    v[6] = (short)f2b(b.z); v[7] = (short)f2b(b.w);
    return v;
}
static __device__ __forceinline__ f32x4 zero4() {
    f32x4 z; z[0] = 0.f; z[1] = 0.f; z[2] = 0.f; z[3] = 0.f; return z;
}

// mask dtype probe: reference dtype is bool; harness may ship 1-byte bool or
// int32 (0/1). If int32, bytes at non-word-aligned offsets are all zero.
__global__ void detect_mask_kernel(const unsigned char* __restrict__ m, int* flag) {
    const int t = threadIdx.x;   // 64 threads, inspect first 1024 bytes
    int nz = 0;
#pragma unroll
    for (int i = 0; i < 16; ++i) {
        const int idx = t * 16 + i;
        if (idx & 3) nz |= m[idx];
    }
    const unsigned long long b = __ballot(nz != 0);
    if (t == 0) *flag = (b == 0ULL) ? 1 : 0;   // 1 => int32-encoded mask
}

// Convert W1/W2/W3 (fp32 row-major [256][256]) to bf16 in MFMA fragment order:
// Wb[m][o_blk][kt][lane][8] with element = W[o_blk*16 + (lane&15)][kt*32 + (lane>>4)*8 + j].
// A wave's fragment load becomes lane*16B contiguous -> one coalesced 1KB read.
// W2/W3 pre-scaled by 0.1 (the reference's z2/z3 factor).
__global__ void prep_w_kernel(const float* __restrict__ W1,
                              const float* __restrict__ W2,
                              const float* __restrict__ W3,
                              unsigned short* __restrict__ Wb) {
    const int gid = blockIdx.x * 256 + threadIdx.x;   // 3*8192 groups of 8
    const int m = gid >> 13;
    const int g = gid & 8191;
    const int o_blk = g >> 9;
    const int kt = (g >> 6) & 7;
    const int lane = g & 63;
    const int lm = lane & 15, quad = lane >> 4;
    const float* W = (m == 0) ? W1 : ((m == 1) ? W2 : W3);
    const float sc = (m == 0) ? 1.0f : 0.1f;
    const float* p = W + (o_blk * 16 + lm) * C_IN + kt * 32 + quad * 8;
    bf16x8 v;
#pragma unroll
    for (int j = 0; j < 8; ++j) v[j] = (short)f2b(p[j] * sc);
    *(bf16x8*)(Wb + (size_t)m * WB_MAT_ELEMS + (size_t)g * 8) = v;
}

__global__ __launch_bounds__(256, 4)
void fused_utou_kernel(const float* __restrict__ u,
                       const float* __restrict__ n_batch,
                       const unsigned short* __restrict__ Wb,   // [3][16][8][64][8] bf16
                       const float* __restrict__ b1,
                       const void* __restrict__ maskp,
                       const int* __restrict__ coloring,
                       const int* __restrict__ mask_flag,
                       float* __restrict__ out)
{
    // Flat LDS: [A2: 4 rows x APITCH][Abuf: 64 rows x APITCH] (bf16).
    // A2 fragment reads at rows 4..15 alias into Abuf -> garbage feeding only
    // C rows 4..15, which are never read.
    __shared__ unsigned short smem[(4 + ROWS) * APITCH];        // 35904 B
    __shared__ unsigned short zb[2][NODES_PER_BLOCK][C_IN];     // z2/z3, bf16, 4096 B
    unsigned short* A2 = smem;
    unsigned short* Ab = smem + 4 * APITCH;

    const int t = threadIdx.x;
    const int nb = blockIdx.x * NODES_PER_BLOCK;
    const long long row0 = (long long)nb * K_COL;
    const int wv = t >> 6;
    const int l = t & 63;
    const int lm = l & 15;
    const int quad = l >> 4;
    const int obase = wv * 64;         // each wave owns 64 output columns

    // ---- Phase 1: stage u tile fp32->bf16; fp32 mean2 computed in-flight ----
    {
        const int nd = wv;             // node in block == wave id
        const int co = l;              // column quad (4 floats)
        const float inv_nb = 1.0f / n_batch[nb + nd];
        const float* up = u + (row0 + (long long)nd * K_COL) * C_IN + co * 4;
        float s0 = 0.f, s1 = 0.f, s2 = 0.f, s3 = 0.f;
#pragma unroll
        for (int r = 0; r < K_COL; ++r) {
            const float4 v = *(const float4*)(up + r * C_IN);  // wave reads full 1KB row
            s0 += v.x; s1 += v.y; s2 += v.z; s3 += v.w;
            ushort4 h;
            h.x = f2b(v.x); h.y = f2b(v.y); h.z = f2b(v.z); h.w = f2b(v.w);
            *(ushort4*)&Ab[(nd * K_COL + r) * APITCH + co * 4] = h;
        }
        ushort4 m;
        m.x = f2b(s0 * inv_nb); m.y = f2b(s1 * inv_nb);
        m.z = f2b(s2 * inv_nb); m.w = f2b(s3 * inv_nb);
        *(ushort4*)&A2[nd * APITCH + co * 4] = m;
    }
    __syncthreads();

    const unsigned short* Wb1 = Wb;
    const unsigned short* Wb2 = Wb + WB_MAT_ELEMS;
    const unsigned short* Wb3 = Wb + 2 * WB_MAT_ELEMS;

    // ---- Phase 2: z2 = mean2@(0.1*W2)^T, z3 = mean2@(0.1*W3)^T ----
    {
        f32x4 acc2[4] = {zero4(), zero4(), zero4(), zero4()};
        f32x4 acc3[4] = {zero4(), zero4(), zero4(), zero4()};
#pragma unroll
        for (int kt = 0; kt < 8; ++kt) {
            const bf16x8 a2 = *(const bf16x8*)&A2[lm * APITCH + kt * 32 + quad * 8];
#pragma unroll
            for (int nt = 0; nt < 4; ++nt) {
                const int ob = wv * 4 + nt;
                const bf16x8 b2 = *(const bf16x8*)(Wb2 + ((ob * 8 + kt) * 64 + l) * 8);
                acc2[nt] = __builtin_amdgcn_mfma_f32_16x16x32_bf16(a2, b2, acc2[nt], 0, 0, 0);
                const bf16x8 b3 = *(const bf16x8*)(Wb3 + ((ob * 8 + kt) * 64 + l) * 8);
                acc3[nt] = __builtin_amdgcn_mfma_f32_16x16x32_bf16(a2, b3, acc3[nt], 0, 0, 0);
            }
        }
        // C/D: col = lane&15, row = quad*4 + reg. Mean rows 0..3 live in quad 0.
        if (quad == 0) {
#pragma unroll
            for (int nt = 0; nt < 4; ++nt) {
#pragma unroll
                for (int r = 0; r < 4; ++r) {
                    const int col = obase + nt * 16 + lm;
                    zb[0][r][col] = f2b(acc2[nt][r]);
                    zb[1][r][col] = f2b(acc3[nt][r]);
                }
            }
        }
    }
    __syncthreads();

    // ---- Phase 3: main GEMM [64 x 256] @ W1^T, coalesced bf16 frags from L2 ----
    f32x4 acc[4][4];
#pragma unroll
    for (int mt = 0; mt < 4; ++mt)
#pragma unroll
        for (int nt = 0; nt < 4; ++nt) acc[mt][nt] = zero4();

#pragma unroll
    for (int kt = 0; kt < 8; ++kt) {
        bf16x8 bfr[4];
#pragma unroll
        for (int nt = 0; nt < 4; ++nt)
            bfr[nt] = *(const bf16x8*)(Wb1 + (((wv * 4 + nt) * 8 + kt) * 64 + l) * 8);
        const int kof = kt * 32 + quad * 8;
#pragma unroll
        for (int mt = 0; mt < 4; ++mt) {
            const bf16x8 af = *(const bf16x8*)&Ab[(mt * 16 + lm) * APITCH + kof];
#pragma unroll
            for (int nt = 0; nt < 4; ++nt)
                acc[mt][nt] = __builtin_amdgcn_mfma_f32_16x16x32_bf16(af, bfr[nt], acc[mt][nt], 0, 0, 0);
        }
    }

    // ---- Phase 4: epilogue  u + out + b1 + scatter(z2) + mask*z3 ----
    const bool mask_is_i32 = (*mask_flag != 0);
    const int* mi = (const int*)maskp;
    const unsigned char* mb = (const unsigned char*)maskp;
    float b1v[4];
#pragma unroll
    for (int nt = 0; nt < 4; ++nt) b1v[nt] = b1[obase + nt * 16 + lm];

#pragma unroll
    for (int mt = 0; mt < 4; ++mt) {
#pragma unroll
        for (int r = 0; r < 4; ++r) {
            const int row = mt * 16 + quad * 4 + r;   // tile row = M index
            const int node = mt;                      // == row >> 4
            const int kc = row & 15;
            const long long rg = row0 + row;          // flat (n,k) == mask index
            const bool sel = (coloring[nb + node] == kc);
            const bool mk = mask_is_i32 ? (mi[rg] != 0) : (mb[rg] != 0);
            float* orow = out + rg * C_IN;
#pragma unroll
            for (int nt = 0; nt < 4; ++nt) {
                const int col = obase + nt * 16 + lm;
                float v = acc[mt][nt][r] + b1v[nt] + b2f(Ab[row * APITCH + col]);
                v += sel ? b2f(zb[0][node][col]) : 0.0f;
                v += mk ? b2f(zb[1][node][col]) : 0.0f;
                orow[col] = v;
            }
        }
    }
}

// ---- Fallback (round-1 verified kernel) if ws can't hold bf16 weights ----
__global__ __launch_bounds__(256, 2)
void fused_utou_fallback(const float* __restrict__ u,
                         const float* __restrict__ n_batch,
                         const float* __restrict__ W1,
                         const float* __restrict__ b1,
                         const float* __restrict__ W2,
                         const float* __restrict__ W3,
                         const void* __restrict__ maskp,
                         const int* __restrict__ coloring,
                         const int* __restrict__ mask_flag,
                         float* __restrict__ out)
{
    __shared__ unsigned short Abuf[ROWS][APITCH];
    __shared__ unsigned short A2buf[16][APITCH];
    __shared__ float zbuf2[NODES_PER_BLOCK][ZPITCH];
    __shared__ float zbuf3[NODES_PER_BLOCK][ZPITCH];

    const int t = threadIdx.x;
    const int nb = blockIdx.x * NODES_PER_BLOCK;
    const long long row0 = (long long)nb * K_COL;

    {
        const int nd = t >> 6;
        const int co = t & 63;
        const float inv_nb = 1.0f / n_batch[nb + nd];
        const float* up = u + (row0 + (long long)nd * K_COL) * C_IN + co * 4;
        float s0 = 0.f, s1 = 0.f, s2 = 0.f, s3 = 0.f;
#pragma unroll
        for (int r = 0; r < K_COL; ++r) {
            const float4 v = *(const float4*)(up + r * C_IN);
            s0 += v.x; s1 += v.y; s2 += v.z; s3 += v.w;
            ushort4 h;
            h.x = f2b(v.x); h.y = f2b(v.y); h.z = f2b(v.z); h.w = f2b(v.w);
            *(ushort4*)&Abuf[nd * K_COL + r][co * 4] = h;
        }
        ushort4 m;
        m.x = f2b(s0 * inv_nb); m.y = f2b(s1 * inv_nb);
        m.z = f2b(s2 * inv_nb); m.w = f2b(s3 * inv_nb);
        *(ushort4*)&A2buf[nd][co * 4] = m;
    }
    __syncthreads();

    const int l = t & 63;
    const int lm = l & 15;
    const int quad = l >> 4;
    const int obase = (t >> 6) * 64;

    {
        f32x4 acc2[4] = {zero4(), zero4(), zero4(), zero4()};
        f32x4 acc3[4] = {zero4(), zero4(), zero4(), zero4()};
#pragma unroll
        for (int kt = 0; kt < 8; ++kt) {
            const int kof = kt * 32 + quad * 8;
            const bf16x8 a2 = *(const bf16x8*)&A2buf[lm][kof];
#pragma unroll
            for (int nt = 0; nt < 4; ++nt) {
                const int o = obase + nt * 16 + lm;
                const bf16x8 b2 = cvt8(W2 + o * C_IN + kof);
                acc2[nt] = __builtin_amdgcn_mfma_f32_16x16x32_bf16(a2, b2, acc2[nt], 0, 0, 0);
                const bf16x8 b3 = cvt8(W3 + o * C_IN + kof);
                acc3[nt] = __builtin_amdgcn_mfma_f32_16x16x32_bf16(a2, b3, acc3[nt], 0, 0, 0);
            }
        }
        if (quad == 0) {
#pragma unroll
            for (int nt = 0; nt < 4; ++nt) {
#pragma unroll
                for (int r = 0; r < 4; ++r) {
                    const int col = obase + nt * 16 + lm;
                    zbuf2[r][col] = 0.1f * acc2[nt][r];
                    zbuf3[r][col] = 0.1f * acc3[nt][r];
                }
            }
        }
    }
    __syncthreads();

    f32x4 acc[4][4];
#pragma unroll
    for (int mt = 0; mt < 4; ++mt)
#pragma unroll
        for (int nt = 0; nt < 4; ++nt) acc[mt][nt] = zero4();

#pragma unroll
    for (int kt = 0; kt < 8; ++kt) {
        const int kof = kt * 32 + quad * 8;
        bf16x8 bfr[4];
#pragma unroll
        for (int nt = 0; nt < 4; ++nt)
            bfr[nt] = cvt8(W1 + (obase + nt * 16 + lm) * C_IN + kof);
#pragma unroll
        for (int mt = 0; mt < 4; ++mt) {
            const bf16x8 af = *(const bf16x8*)&Abuf[mt * 16 + lm][kof];
#pragma unroll
            for (int nt = 0; nt < 4; ++nt)
                acc[mt][nt] = __builtin_amdgcn_mfma_f32_16x16x32_bf16(af, bfr[nt], acc[mt][nt], 0, 0, 0);
        }
    }

    const bool mask_is_i32 = (*mask_flag != 0);
    const int* mi = (const int*)maskp;
    const unsigned char* mb = (const unsigned char*)maskp;
    float b1v[4];
#pragma unroll
    for (int nt = 0; nt < 4; ++nt) b1v[nt] = b1[obase + nt * 16 + lm];

#pragma unroll
    for (int mt = 0; mt < 4; ++mt) {
#pragma unroll
        for (int r = 0; r < 4; ++r) {
            const int row = mt * 16 + quad * 4 + r;
            const int node = row >> 4;
            const int kc = row & 15;
            const long long rg = row0 + row;
            const bool sel = (coloring[nb + node] == kc);
            const bool mk = mask_is_i32 ? (mi[rg] != 0) : (mb[rg] != 0);
            float* orow = out + rg * C_IN;
#pragma unroll
            for (int nt = 0; nt < 4; ++nt) {
                const int col = obase + nt * 16 + lm;
                float v = acc[mt][nt][r] + b1v[nt] + b2f(Abuf[row][col]);
                v += sel ? zbuf2[node][col] : 0.0f;
                v += mk ? zbuf3[node][col] : 0.0f;
                orow[col] = v;
            }
        }
    }
}

extern "C" void kernel_launch(void* const* d_in, const int* in_sizes, int n_in,
                              void* d_out, int out_size, void* d_ws, size_t ws_size,
                              hipStream_t stream) {
    const float* u        = (const float*)d_in[0];
    const float* nbt      = (const float*)d_in[1];
    const float* W1       = (const float*)d_in[2];
    const float* b1       = (const float*)d_in[3];
    const float* W2       = (const float*)d_in[4];
    const float* W3       = (const float*)d_in[5];
    const void*  mask     = d_in[6];
    const int*   coloring = (const int*)d_in[7];
    float* out = (float*)d_out;
    int* flag = (int*)((char*)d_ws + WS_FLAG_OFF);

    detect_mask_kernel<<<1, 64, 0, stream>>>((const unsigned char*)mask, flag);
    if (ws_size >= (size_t)WS_NEEDED) {
        unsigned short* Wb = (unsigned short*)((char*)d_ws + WS_WB_OFF);
        prep_w_kernel<<<96, 256, 0, stream>>>(W1, W2, W3, Wb);
        fused_utou_kernel<<<N_NODES / NODES_PER_BLOCK, 256, 0, stream>>>(
            u, nbt, Wb, b1, mask, coloring, flag, out);
    } else {
        fused_utou_fallback<<<N_NODES / NODES_PER_BLOCK, 256, 0, stream>>>(
            u, nbt, W1, b1, W2, W3, mask, coloring, flag, out);
    }
}